// Round 1
// baseline (2555.458 us; speedup 1.0000x reference)
//
#include <hip/hip_runtime.h>

#define NUM_CLASSES 19
#define FEAT_CH 512
#define ACC_SLOTS (NUM_CLASSES * FEAT_CH)  // 9728
#define CNT_STRIDE 32                      // padded per-slab count vector

constexpr int BLOCK = 512;
constexpr int NBLK  = 1024;  // 4 blocks/CU * 256 CUs; 38KB LDS -> exactly 4/CU, 32 waves/CU

// Stage 1: block-local LDS accumulation, then flush to a PRIVATE per-block slab
// with plain coalesced stores (no contended global atomics).
// Main loop is branchless: features loaded unconditionally (clamped index),
// scaled by validity weight -> label load and feature load are independent,
// 2 float4 loads in flight per wave per iteration.
// LDS layout swizzle: channel (4*cg + j) stored at [class*512 + j*128 + cg]
// so ds_add_f32 addresses are stride-1 across lanes (2 lanes/bank = free).
__global__ __launch_bounds__(BLOCK, 8)
void bars_accum_kernel(const float* __restrict__ feat,
                       const int* __restrict__ labels,
                       const int* __restrict__ ignore_p,
                       float* __restrict__ part,   // [K][ACC_SLOTS] natural layout
                       float* __restrict__ cnts,   // [K][CNT_STRIDE]
                       int n, int K) {
    __shared__ float ssum[ACC_SLOTS];
    __shared__ float scnt[NUM_CLASSES];

    const int tid = threadIdx.x;
    for (int s = tid; s < ACC_SLOTS; s += BLOCK) ssum[s] = 0.f;
    if (tid < NUM_CLASSES) scnt[tid] = 0.f;
    __syncthreads();

    const int ign = ignore_p[0];

    // contiguous pixel chunk per block (L2/TLB friendly streaming)
    const int per_blk = (n + (int)gridDim.x - 1) / (int)gridDim.x;
    const int p_begin = (int)blockIdx.x * per_blk;
    const int p_end   = min(n, p_begin + per_blk);

    const int sub = tid >> 7;   // which of 4 pixels in a quad (wave-uniform)
    const int cg  = tid & 127;  // float4 channel-group
    const float4* __restrict__ feat4 = (const float4*)feat;

    for (int p0 = p_begin; p0 < p_end; p0 += 8) {
        const int pa  = p0 + sub;
        const int pb  = p0 + 4 + sub;
        const int pca = min(pa, p_end - 1);   // clamp: loads always in-bounds
        const int pcb = min(pb, p_end - 1);
        const int la  = labels[pca];          // independent of feat loads
        const int lb  = labels[pcb];
        const float4 va = feat4[(size_t)pca * (FEAT_CH / 4) + cg];  // unconditional
        const float4 vb = feat4[(size_t)pcb * (FEAT_CH / 4) + cg];
        const float wa = (la != ign && pa < p_end) ? 1.f : 0.f;
        const float wb = (lb != ign && pb < p_end) ? 1.f : 0.f;
        const int   ca = (la != ign) ? la : 0;  // ignored -> bucket 0 with weight 0
        const int   cb = (lb != ign) ? lb : 0;
        float* da = &ssum[ca * FEAT_CH];
        float* db = &ssum[cb * FEAT_CH];
        atomicAdd(&da[0 * 128 + cg], va.x * wa);  // ds_add_f32, stride-1 banks
        atomicAdd(&da[1 * 128 + cg], va.y * wa);
        atomicAdd(&da[2 * 128 + cg], va.z * wa);
        atomicAdd(&da[3 * 128 + cg], va.w * wa);
        atomicAdd(&db[0 * 128 + cg], vb.x * wb);
        atomicAdd(&db[1 * 128 + cg], vb.y * wb);
        atomicAdd(&db[2 * 128 + cg], vb.z * wb);
        atomicAdd(&db[3 * 128 + cg], vb.w * wb);
        if (cg == 0) {
            atomicAdd(&scnt[ca], wa);
            atomicAdd(&scnt[cb], wb);
        }
    }
    __syncthreads();

    // Flush LDS partials (un-swizzle to natural c*512+ch).
    const int slab = (int)blockIdx.x % K;
    float* __restrict__ ps = part + (size_t)slab * ACC_SLOTS;
    if (K == (int)gridDim.x) {
        // private slab: plain coalesced stores, zero contention
        for (int g = tid; g < ACC_SLOTS; g += BLOCK) {
            const int c = g >> 9, ch = g & 511, j = ch & 3, cgf = ch >> 2;
            ps[g] = ssum[c * FEAT_CH + j * 128 + cgf];
        }
        if (tid < NUM_CLASSES) cnts[(size_t)slab * CNT_STRIDE + tid] = scnt[tid];
    } else {
        // fallback (small workspace): replicated slabs, reduced contention
        for (int g = tid; g < ACC_SLOTS; g += BLOCK) {
            const int c = g >> 9, ch = g & 511, j = ch & 3, cgf = ch >> 2;
            const float v = ssum[c * FEAT_CH + j * 128 + cgf];
            if (v != 0.f) atomicAdd(&ps[g], v);
        }
        if (tid < NUM_CLASSES) {
            const float c = scnt[tid];
            if (c != 0.f) atomicAdd(&cnts[(size_t)slab * CNT_STRIDE + tid], c);
        }
    }
}

// Stage 2: reduce the K slabs and finalize mean / sum_weight / class_dist.
// Grid: ACC_SLOTS/256 = 38 blocks; for fixed k, thread loads are fully coalesced.
__global__ __launch_bounds__(256)
void bars_reduce_kernel(const float* __restrict__ part,
                        const float* __restrict__ cnts,
                        float* __restrict__ out, int K) {
    __shared__ float scnt[NUM_CLASSES];
    const int tid = threadIdx.x;
    if (tid < NUM_CLASSES) scnt[tid] = 0.f;
    __syncthreads();

    // counts: cnts[k*32 + c]. 256 % 32 == 0 -> each thread reads one fixed c.
    const int c = tid & (CNT_STRIDE - 1);
    float cacc = 0.f;
    for (int idx = tid; idx < K * CNT_STRIDE; idx += 256)
        cacc += cnts[idx];
    if (c < NUM_CLASSES) atomicAdd(&scnt[c], cacc);
    __syncthreads();

    const int g = (int)blockIdx.x * 256 + tid;  // ACC_SLOTS = 38*256 exactly
    float a0 = 0.f, a1 = 0.f, a2 = 0.f, a3 = 0.f;
    int k = 0;
    for (; k + 4 <= K; k += 4) {  // 4 independent streams for MLP
        a0 += part[(size_t)(k + 0) * ACC_SLOTS + g];
        a1 += part[(size_t)(k + 1) * ACC_SLOTS + g];
        a2 += part[(size_t)(k + 2) * ACC_SLOTS + g];
        a3 += part[(size_t)(k + 3) * ACC_SLOTS + g];
    }
    for (; k < K; ++k) a0 += part[(size_t)k * ACC_SLOTS + g];
    const float s   = (a0 + a1) + (a2 + a3);
    const float cnt = scnt[g >> 9];               // class of this slot (uniform per block)
    const float amt = (cnt == 0.f) ? 1.f : cnt;
    out[g] = s / amt;                             // mean
    out[ACC_SLOTS + g] = cnt;                     // sum_weight (broadcast counts)
    if (blockIdx.x == 0 && tid < NUM_CLASSES)
        out[2 * ACC_SLOTS + tid] = scnt[tid];     // class_dist
}

extern "C" void kernel_launch(void* const* d_in, const int* in_sizes, int n_in,
                              void* d_out, int out_size, void* d_ws, size_t ws_size,
                              hipStream_t stream) {
    const float* feat   = (const float*)d_in[0];
    const int*   labels = (const int*)d_in[1];
    const int*   ign    = (const int*)d_in[2];
    float*       out    = (float*)d_out;

    const int n = in_sizes[1];  // number of pixels (labels element count)

    const size_t slab_bytes = (size_t)(ACC_SLOTS + CNT_STRIDE) * sizeof(float);
    int K = (int)(ws_size / slab_bytes);
    if (K > NBLK) K = NBLK;
    if (K < 1)    K = 1;

    float* part = (float*)d_ws;
    float* cnts = part + (size_t)K * ACC_SLOTS;

    if (K < NBLK) {
        // only the atomic fallback needs zeroed accumulators
        hipMemsetAsync(d_ws, 0, (size_t)K * slab_bytes, stream);
    }
    bars_accum_kernel<<<NBLK, BLOCK, 0, stream>>>(feat, labels, ign, part, cnts, n, K);
    bars_reduce_kernel<<<ACC_SLOTS / 256, 256, 0, stream>>>(part, cnts, out, K);
}